// Round 5
// baseline (1914.231 us; speedup 1.0000x reference)
//
#include <hip/hip_runtime.h>

constexpr int Nn = 50000;
constexpr int Ee = 800000;
constexpr int Qq = 2000000;
constexpr int Gg = 64;
constexpr int Hh = 128;

typedef short bf16x8 __attribute__((ext_vector_type(8)));
typedef float f32x4  __attribute__((ext_vector_type(4)));

__device__ __forceinline__ unsigned short f2bf(float f) {
    unsigned u = __builtin_bit_cast(unsigned, f);
    u += 0x7FFFu + ((u >> 16) & 1u);
    return (unsigned short)(u >> 16);
}
__device__ __forceinline__ float bf2f(unsigned short s) {
    unsigned u = ((unsigned)s) << 16;
    return __builtin_bit_cast(float, u);
}

__device__ __forceinline__ void bar_raw() {
    asm volatile("" ::: "memory");
    __builtin_amdgcn_s_barrier();
    asm volatile("" ::: "memory");
}
__device__ __forceinline__ void wait_lds() {
    asm volatile("s_waitcnt lgkmcnt(0)" ::: "memory");
}

// ---------------- counting sort: histogram ----------------
__global__ void k_hist(const int* __restrict__ idx, int n, int limit,
                       int* __restrict__ hist) {
    int i = blockIdx.x * blockDim.x + threadIdx.x;
    if (i < n) { int v = idx[i]; if (v < limit) atomicAdd(&hist[v], 1); }
}

// ---------------- counting sort: single-block exclusive scan over Nn bins ----------------
__global__ __launch_bounds__(1024) void k_scan(const int* __restrict__ hist,
                                               int* __restrict__ cursor,
                                               int* __restrict__ total) {
    __shared__ int s[1024];
    const int tid = threadIdx.x;
    const int per = (Nn + 1023) / 1024;
    int start = tid * per, end = min(start + per, Nn);
    int sum = 0;
    for (int i = start; i < end; ++i) sum += hist[i];
    s[tid] = sum;
    __syncthreads();
    for (int off = 1; off < 1024; off <<= 1) {
        int v = (tid >= off) ? s[tid - off] : 0;
        __syncthreads();
        s[tid] += v;
        __syncthreads();
    }
    int base = s[tid] - sum;
    for (int i = start; i < end; ++i) {
        cursor[i] = base;
        base += hist[i];
    }
    if (tid == 1023 && total) *total = s[1023];
}

// ---------------- counting sort: scatter ----------------
__global__ void k_scatter(const int* __restrict__ idx, int n, int limit,
                          int* __restrict__ cursor, int* __restrict__ perm) {
    int i = blockIdx.x * blockDim.x + threadIdx.x;
    if (i < n) {
        int v = idx[i];
        if (v < limit) { int p = atomicAdd(&cursor[v], 1); perm[p] = i; }
    }
}

// ---------------- weight transpose+pad to bf16 [128][Kp] (k-contiguous) ----------------
__global__ void k_wt(const float* __restrict__ in, unsigned short* __restrict__ out,
                     int K, int Kp) {
    int idx = blockIdx.x * blockDim.x + threadIdx.x;
    if (idx >= 128 * Kp) return;
    int n = idx / Kp, k = idx - n * Kp;
    out[idx] = (k < K) ? f2bf(in[(size_t)k * 128 + n]) : (unsigned short)0;
}

// ---------------- x -> bf16 h0 ----------------
__global__ void k_h0(const float* __restrict__ x, unsigned short* __restrict__ hb) {
    int idx = blockIdx.x * blockDim.x + threadIdx.x;
    if (idx < Nn * Hh) hb[idx] = f2bf(x[idx]);
}

// ---------------- f32 -> bf16 convert (agg2) ----------------
__global__ void k_cvt(const float* __restrict__ in, unsigned short* __restrict__ out,
                      int n) {
    int i = blockIdx.x * blockDim.x + threadIdx.x;
    if (i * 4 < n) {
        float4 v = *(const float4*)&in[i * 4];
        ushort4 o;
        o.x = f2bf(v.x); o.y = f2bf(v.y); o.z = f2bf(v.z); o.w = f2bf(v.w);
        *(ushort4*)&out[i * 4] = o;
    }
}

// ---------------- fused 2-layer MFMA MLP on a 64-row tile (LDS-staged A) ----------------
template<int K1P, int SA1>
__device__ __forceinline__ void mfma_mlp2(
    const unsigned short* A1, unsigned short* A2,
    const unsigned short* __restrict__ Wa, const float* __restrict__ ba,
    const unsigned short* __restrict__ Wb, const float* __restrict__ bb,
    float accOut[4][2][4])
{
    const int tid  = threadIdx.x;
    const int lane = tid & 63;
    const int wid  = tid >> 6;
    const int nb   = wid * 32;
    const int rA   = lane & 15;
    const int kg   = lane >> 4;     // 0..3

    f32x4 acc[4][2];
#pragma unroll
    for (int rt = 0; rt < 4; ++rt)
#pragma unroll
        for (int ct = 0; ct < 2; ++ct)
            acc[rt][ct] = (f32x4){0.f, 0.f, 0.f, 0.f};

#pragma unroll
    for (int ks = 0; ks < K1P / 32; ++ks) {
        const int k0 = ks * 32 + kg * 8;
        bf16x8 b0 = *(const bf16x8*)&Wa[(size_t)(nb + rA) * K1P + k0];
        bf16x8 b1 = *(const bf16x8*)&Wa[(size_t)(nb + 16 + rA) * K1P + k0];
#pragma unroll
        for (int rt = 0; rt < 4; ++rt) {
            bf16x8 a = *(const bf16x8*)&A1[(rt * 16 + rA) * SA1 + k0];
            acc[rt][0] = __builtin_amdgcn_mfma_f32_16x16x32_bf16(a, b0, acc[rt][0], 0, 0, 0);
            acc[rt][1] = __builtin_amdgcn_mfma_f32_16x16x32_bf16(a, b1, acc[rt][1], 0, 0, 0);
        }
    }
    __syncthreads();            // all A1 reads done before A2 overwrite
#pragma unroll
    for (int rt = 0; rt < 4; ++rt)
#pragma unroll
        for (int ct = 0; ct < 2; ++ct) {
            int col = nb + ct * 16 + rA;
            float bias = ba[col];
#pragma unroll
            for (int i = 0; i < 4; ++i) {
                int row = rt * 16 + kg * 4 + i;
                A2[row * 136 + col] = f2bf(fmaxf(acc[rt][ct][i] + bias, 0.f));
            }
        }
    __syncthreads();

    f32x4 acc2[4][2];
#pragma unroll
    for (int rt = 0; rt < 4; ++rt)
#pragma unroll
        for (int ct = 0; ct < 2; ++ct)
            acc2[rt][ct] = (f32x4){0.f, 0.f, 0.f, 0.f};

#pragma unroll
    for (int ks = 0; ks < 4; ++ks) {
        const int k0 = ks * 32 + kg * 8;
        bf16x8 b0 = *(const bf16x8*)&Wb[(size_t)(nb + rA) * 128 + k0];
        bf16x8 b1 = *(const bf16x8*)&Wb[(size_t)(nb + 16 + rA) * 128 + k0];
#pragma unroll
        for (int rt = 0; rt < 4; ++rt) {
            bf16x8 a = *(const bf16x8*)&A2[(rt * 16 + rA) * 136 + k0];
            acc2[rt][0] = __builtin_amdgcn_mfma_f32_16x16x32_bf16(a, b0, acc2[rt][0], 0, 0, 0);
            acc2[rt][1] = __builtin_amdgcn_mfma_f32_16x16x32_bf16(a, b1, acc2[rt][1], 0, 0, 0);
        }
    }
#pragma unroll
    for (int rt = 0; rt < 4; ++rt)
#pragma unroll
        for (int ct = 0; ct < 2; ++ct) {
            int col = nb + ct * 16 + rA;
            float bias = bb[col];
#pragma unroll
            for (int i = 0; i < 4; ++i)
                accOut[rt][ct][i] = acc2[rt][ct][i] + bias;
        }
}

// ---------------- quadruplet message MLP + scatter into agg2[k_idx] ----------------
__global__ __launch_bounds__(256) void k_quad(
    const unsigned short* __restrict__ hb,
    const float* __restrict__ rbf, const float* __restrict__ cbf, const float* __restrict__ sbf,
    const int* __restrict__ l_idx, const int* __restrict__ k_idx,
    const int* __restrict__ list, const int* __restrict__ cnt,
    const unsigned short* __restrict__ Wa, const float* __restrict__ ba,
    const unsigned short* __restrict__ Wb, const float* __restrict__ bb,
    float* __restrict__ agg2)
{
    __shared__ unsigned short A1[64 * 168];
    __shared__ int rqi[64], rli[64], rki[64];
    const int Qu = *cnt;
    const int tid = threadIdx.x;
    for (int m0 = blockIdx.x * 64; m0 < Qu; m0 += gridDim.x * 64) {
        if (tid < 64) {
            int m = m0 + tid;
            int q = list[min(m, Qu - 1)];
            rqi[tid] = q; rli[tid] = l_idx[q]; rki[tid] = k_idx[q];
        }
        __syncthreads();
        for (int i = tid; i < 64 * 16; i += 256) {
            int row = i >> 4, ch = i & 15;
            *(uint4*)&A1[row * 168 + ch * 8] =
                *(const uint4*)&hb[(size_t)rli[row] * Hh + ch * 8];
        }
        for (int i = tid; i < 64 * 32; i += 256) {
            int row = i >> 5, c = i & 31;
            int q = rqi[row], ki = rki[row];
            float v = 0.f;
            if (c < 6)       v = rbf[(size_t)ki * 6 + c];
            else if (c < 12) v = cbf[(size_t)q * 6 + (c - 6)];
            else if (c < 18) v = sbf[(size_t)q * 6 + (c - 12)];
            A1[row * 168 + 128 + c] = f2bf(v);
        }
        __syncthreads();
        float accOut[4][2][4];
        mfma_mlp2<160, 168>(A1, A1, Wa, ba, Wb, bb, accOut);
        const int lane = tid & 63;
        const int nb = (tid >> 6) * 32;
        const int rA = lane & 15, kg = lane >> 4;
#pragma unroll
        for (int rt = 0; rt < 4; ++rt)
#pragma unroll
            for (int ct = 0; ct < 2; ++ct) {
                int col = nb + ct * 16 + rA;
                float s = 0.f; int cur = -1;
#pragma unroll
                for (int i = 0; i < 4; ++i) {
                    int row = rt * 16 + kg * 4 + i;
                    int tgt = (m0 + row < Qu) ? rki[row] : -1;
                    if (tgt != cur) {
                        if (cur >= 0) atomicAdd(&agg2[(size_t)cur * Hh + col], s);
                        cur = tgt; s = 0.f;
                    }
                    s += (tgt >= 0) ? accOut[rt][ct][i] : 0.f;
                }
                if (cur >= 0) atomicAdd(&agg2[(size_t)cur * Hh + col], s);
            }
        __syncthreads();   // LDS reuse across tile iterations
    }
}

// ================= k_edge: persistent blocks + 1-deep reg-staged pipeline =================
// Single 32KB LDS buffer holds, in sequence (barrier-guarded overlays):
//   gather tile (64 rows x 512B, XOR-swizzled chunks) -> A2 (64x136 bf16) -> Ared (64x128 f32)
// Next tile's gather is loaded into registers at iteration start and written to LDS at the
// tail, with raw s_barrier (no vmcnt drain) so HBM/L3 latency hides under the MFMA work.
__global__ __launch_bounds__(256, 3) void k_edge(
    const unsigned short* __restrict__ hb, const unsigned short* __restrict__ agg2b,
    const int* __restrict__ src, const int* __restrict__ dst,
    const int* __restrict__ perm,
    const unsigned short* __restrict__ Wa, const float* __restrict__ ba,
    const unsigned short* __restrict__ Wb, const float* __restrict__ bb,
    float* __restrict__ aggr)
{
    __shared__ unsigned short BUF[64 * 256];   // 32 KB
    const int tid  = threadIdx.x;
    const int lane = tid & 63;
    const int wid  = tid >> 6;
    const int nb   = wid * 32;
    const int rA   = lane & 15;
    const int kg   = lane >> 4;

    const int NT = Ee / 64;
    const int G  = gridDim.x;
    const int bid = blockIdx.x;
    const int nt = (NT - bid + G - 1) / G;

    // gather geometry: thread covers row rr = tid>>2 (128B = logical chunks q*8..q*8+7)
    const int rr = tid >> 2;          // 0..63
    const int q  = lane & 3;          // 0..3
    const int rx = rr & 15;           // swizzle key (== lane>>2)

    unsigned short* A2 = BUF;
    float* Ared = (float*)BUF;

    int sA, dA, sB, dB, sC, dC;

    // ---- helpers (lambdas keep indices compile-time via unroll) ----
    auto load_idx = [&](int t, int& s, int& d) {
        int r = wid * 16 + (lane & 15);
        int e = perm[t * 64 + r];
        s = src[e]; d = dst[e];
    };
    uint4 g[8];
    auto gather_load = [&](int sHold, int dHold) {
        int srow = __shfl(sHold, lane >> 2);
        int drow = __shfl(dHold, lane >> 2);
        const unsigned short* hrow = hb + (size_t)srow * 128;
        const unsigned short* arow = agg2b + (size_t)drow * 128;
#pragma unroll
        for (int j = 0; j < 8; ++j) {
            int c = q * 8 + j;                       // logical chunk 0..31
            g[j] = (c < 16) ? *(const uint4*)&hrow[c * 8]
                            : *(const uint4*)&arow[(c - 16) * 8];
        }
    };
    auto stage_write = [&]() {
#pragma unroll
        for (int j = 0; j < 8; ++j) {
            int c = q * 8 + j;
            int p = (c & 16) | ((c & 15) ^ rx);      // physical chunk (XOR swizzle)
            *(uint4*)&BUF[rr * 256 + p * 8] = g[j];
        }
    };

    // ---- prolog ----
    load_idx(bid, sA, dA);
    gather_load(sA, dA);
    if (nt > 1) load_idx(bid + G, sB, dB); else { sB = sA; dB = dA; }
    stage_write();
    __syncthreads();

    for (int i = 0; i < nt; ++i) {
        // 1) issue next tile's gather + idx(i+2) loads (stay in flight all iteration)
        if (i + 1 < nt) gather_load(sB, dB);
        if (i + 2 < nt) load_idx(bid + (i + 2) * G, sC, dC); else { sC = sB; dC = dB; }

        // 2) stage-1 GEMM: [64x256] x [256x128]
        f32x4 acc[4][2];
#pragma unroll
        for (int rt = 0; rt < 4; ++rt)
#pragma unroll
            for (int ct = 0; ct < 2; ++ct)
                acc[rt][ct] = (f32x4){0.f, 0.f, 0.f, 0.f};
#pragma unroll
        for (int ks = 0; ks < 8; ++ks) {
            const int k0 = ks * 32 + kg * 8;
            bf16x8 b0 = *(const bf16x8*)&Wa[(size_t)(nb + rA) * 256 + k0];
            bf16x8 b1 = *(const bf16x8*)&Wa[(size_t)(nb + 16 + rA) * 256 + k0];
            const int pch = (ks * 4 + kg);
#pragma unroll
            for (int rt = 0; rt < 4; ++rt) {
                bf16x8 a = *(const bf16x8*)&BUF[(rt * 16 + rA) * 256 + (pch ^ rA) * 8];
                acc[rt][0] = __builtin_amdgcn_mfma_f32_16x16x32_bf16(a, b0, acc[rt][0], 0, 0, 0);
                acc[rt][1] = __builtin_amdgcn_mfma_f32_16x16x32_bf16(a, b1, acc[rt][1], 0, 0, 0);
            }
        }
        bar_raw();                       // stage-1 reads done -> A2 overlay
        // 3) ReLU + bf16 -> A2
#pragma unroll
        for (int rt = 0; rt < 4; ++rt)
#pragma unroll
            for (int ct = 0; ct < 2; ++ct) {
                int col = nb + ct * 16 + rA;
                float bias = ba[col];
#pragma unroll
                for (int ii = 0; ii < 4; ++ii) {
                    int row = rt * 16 + kg * 4 + ii;
                    A2[row * 136 + col] = f2bf(fmaxf(acc[rt][ct][ii] + bias, 0.f));
                }
            }
        wait_lds();
        bar_raw();
        // 4) stage-2 GEMM: [64x128] x [128x128]
        f32x4 acc2[4][2];
#pragma unroll
        for (int rt = 0; rt < 4; ++rt)
#pragma unroll
            for (int ct = 0; ct < 2; ++ct)
                acc2[rt][ct] = (f32x4){0.f, 0.f, 0.f, 0.f};
#pragma unroll
        for (int ks = 0; ks < 4; ++ks) {
            const int k0 = ks * 32 + kg * 8;
            bf16x8 b0 = *(const bf16x8*)&Wb[(size_t)(nb + rA) * 128 + k0];
            bf16x8 b1 = *(const bf16x8*)&Wb[(size_t)(nb + 16 + rA) * 128 + k0];
#pragma unroll
            for (int rt = 0; rt < 4; ++rt) {
                bf16x8 a = *(const bf16x8*)&A2[(rt * 16 + rA) * 136 + k0];
                acc2[rt][0] = __builtin_amdgcn_mfma_f32_16x16x32_bf16(a, b0, acc2[rt][0], 0, 0, 0);
                acc2[rt][1] = __builtin_amdgcn_mfma_f32_16x16x32_bf16(a, b1, acc2[rt][1], 0, 0, 0);
            }
        }
        bar_raw();                       // stage-2 reads done -> Ared overlay
        // 5) bias + dump to Ared (kg<<4 column XOR to break bank aliasing)
#pragma unroll
        for (int rt = 0; rt < 4; ++rt)
#pragma unroll
            for (int ct = 0; ct < 2; ++ct) {
                int col = nb + ct * 16 + rA;
                float bias = bb[col];
#pragma unroll
                for (int ii = 0; ii < 4; ++ii) {
                    int row = rt * 16 + kg * 4 + ii;
                    Ared[row * 128 + ((col ^ (kg << 4)))] = acc2[rt][ct][ii] + bias;
                }
            }
        wait_lds();
        bar_raw();
        // 6) per-wave run-length segmented reduce over own 16 rows (dst-sorted)
        {
            int c0 = 2 * lane;
            float s0 = 0.f, s1 = 0.f;
            int cur = __shfl(dA, 0);
#pragma unroll
            for (int r = 0; r < 16; ++r) {
                int dr = __shfl(dA, r);
                int key = ((r >> 2) & 3) << 4;
                float2 v = *(const float2*)&Ared[(wid * 16 + r) * 128 + (c0 ^ key)];
                if (dr != cur) {
                    atomicAdd(&aggr[(size_t)cur * 128 + c0], s0);
                    atomicAdd(&aggr[(size_t)cur * 128 + c0 + 1], s1);
                    cur = dr; s0 = 0.f; s1 = 0.f;
                }
                s0 += v.x; s1 += v.y;
            }
            atomicAdd(&aggr[(size_t)cur * 128 + c0], s0);
            atomicAdd(&aggr[(size_t)cur * 128 + c0 + 1], s1);
        }
        bar_raw();                       // Ared reads done -> gather overlay
        // 7) write staged next tile into LDS
        if (i + 1 < nt) { stage_write(); wait_lds(); }
        bar_raw();
        sA = sB; dA = dB; sB = sC; dB = dC;
    }
}

// ---------------- node update MLP -> bf16 h ----------------
__global__ __launch_bounds__(256) void k_node(
    const unsigned short* __restrict__ hb, const float* __restrict__ aggr,
    const unsigned short* __restrict__ Wa, const float* __restrict__ ba,
    const unsigned short* __restrict__ Wb, const float* __restrict__ bb,
    unsigned short* __restrict__ hnew)
{
    __shared__ unsigned short A1[64 * 264];
    const int m0 = blockIdx.x * 64;
    const int tid = threadIdx.x;
    for (int i = tid; i < 64 * 16; i += 256) {
        int row = i >> 4, ch = i & 15;
        int n = min(m0 + row, Nn - 1);
        *(uint4*)&A1[row * 264 + ch * 8] =
            *(const uint4*)&hb[(size_t)n * Hh + ch * 8];
    }
    for (int i = tid; i < 64 * 32; i += 256) {
        int row = i >> 5, c = i & 31;
        int n = min(m0 + row, Nn - 1);
        float4 v = *(const float4*)&aggr[(size_t)n * Hh + c * 4];
        ushort4 o;
        o.x = f2bf(v.x); o.y = f2bf(v.y); o.z = f2bf(v.z); o.w = f2bf(v.w);
        *(ushort4*)&A1[row * 264 + 128 + c * 4] = o;
    }
    __syncthreads();
    float accOut[4][2][4];
    mfma_mlp2<256, 264>(A1, A1, Wa, ba, Wb, bb, accOut);
    const int lane = tid & 63;
    const int nb = (tid >> 6) * 32;
    const int rA = lane & 15, kg = lane >> 4;
#pragma unroll
    for (int rt = 0; rt < 4; ++rt)
#pragma unroll
        for (int ct = 0; ct < 2; ++ct) {
            int col = nb + ct * 16 + rA;
#pragma unroll
            for (int i = 0; i < 4; ++i) {
                int row = rt * 16 + kg * 4 + i;
                int n = m0 + row;
                if (n < Nn)
                    hnew[(size_t)n * Hh + col] = f2bf(accOut[rt][ct][i]);
            }
        }
}

// ---------------- global mean pool: run-length segmented reduction ----------------
__global__ __launch_bounds__(256) void k_pool(const unsigned short* __restrict__ hb,
                                              const int* __restrict__ batch,
                                              float* __restrict__ pooled,
                                              float* __restrict__ cntg) {
    __shared__ int bseg[200];
    constexpr int CH = 196;
    const int start = blockIdx.x * CH;
    const int end = min(start + CH, Nn);
    if (start >= end) return;
    const int tid = threadIdx.x;
    for (int i = tid; i < end - start; i += 256) bseg[i] = batch[start + i];
    __syncthreads();
    const int j = tid & 127;
    const int rh = tid >> 7;
    float acc = 0.f, cacc = 0.f;
    int cur = -1;
    for (int n = start + rh; n < end; n += 2) {
        int g = bseg[n - start];
        if (g != cur) {
            if (cur >= 0) {
                atomicAdd(&pooled[cur * Hh + j], acc);
                if (j == 0) atomicAdd(&cntg[cur], cacc);
            }
            cur = g; acc = 0.f; cacc = 0.f;
        }
        acc += bf2f(hb[(size_t)n * Hh + j]);
        cacc += 1.f;
    }
    if (cur >= 0) {
        atomicAdd(&pooled[cur * Hh + j], acc);
        if (j == 0) atomicAdd(&cntg[cur], cacc);
    }
}

// ---------------- final per-graph MLP ----------------
__global__ __launch_bounds__(128) void k_final(
    const float* __restrict__ pooled, const float* __restrict__ cntg,
    const float* __restrict__ Woa, const float* __restrict__ boa,
    const float* __restrict__ Wob, const float* __restrict__ bob,
    float* __restrict__ out)
{
    __shared__ float p[128];
    __shared__ float t[128];
    __shared__ float red[128];
    const int g = blockIdx.x;
    const int j = threadIdx.x;
    float c = fmaxf(cntg[g], 1.f);
    p[j] = fmaxf(pooled[g * Hh + j] / c, 0.f);
    __syncthreads();
    float acc = boa[j];
    for (int d = 0; d < Hh; ++d) acc = fmaf(p[d], Woa[d * Hh + j], acc);
    t[j] = fmaxf(acc, 0.f);
    __syncthreads();
    red[j] = t[j] * Wob[j];
    __syncthreads();
    for (int s = 64; s > 0; s >>= 1) {
        if (j < s) red[j] += red[j + s];
        __syncthreads();
    }
    if (j == 0) out[g] = red[0] + bob[0];
}

extern "C" void kernel_launch(void* const* d_in, const int* in_sizes, int n_in,
                              void* d_out, int out_size, void* d_ws, size_t ws_size,
                              hipStream_t stream) {
    const float* x     = (const float*)d_in[0];
    const float* rbf   = (const float*)d_in[1];
    const float* cbf   = (const float*)d_in[2];
    const float* sbf   = (const float*)d_in[3];
    const int*   eidx  = (const int*)d_in[4];
    const int*   l_idx = (const int*)d_in[5];
    const int*   k_idx = (const int*)d_in[6];
    const int*   batch = (const int*)d_in[7];
    const float* W_e1a = (const float*)d_in[8];
    const float* b_e1a = (const float*)d_in[9];
    const float* W_e1b = (const float*)d_in[10];
    const float* b_e1b = (const float*)d_in[11];
    const float* W_e2a = (const float*)d_in[12];
    const float* b_e2a = (const float*)d_in[13];
    const float* W_e2b = (const float*)d_in[14];
    const float* b_e2b = (const float*)d_in[15];
    const float* W_na  = (const float*)d_in[16];
    const float* b_na  = (const float*)d_in[17];
    const float* W_nb  = (const float*)d_in[18];
    const float* b_nb  = (const float*)d_in[19];
    const float* W_oa  = (const float*)d_in[20];
    const float* b_oa  = (const float*)d_in[21];
    const float* W_ob  = (const float*)d_in[22];
    const float* b_ob  = (const float*)d_in[23];

    const int* src = eidx;
    const int* dst = eidx + Ee;

    const size_t NHf = (size_t)Nn * Hh * sizeof(float);
    const size_t NHb = (size_t)Nn * Hh * sizeof(unsigned short);
    char* w = (char*)d_ws;
    unsigned short* hb0   = (unsigned short*)w; w += NHb;
    unsigned short* hb1   = (unsigned short*)w; w += NHb;
    float* agg2   = (float*)w; w += NHf;
    unsigned short* agg2b = (unsigned short*)w; w += NHb;
    float* aggr   = (float*)w; w += NHf;
    float* pooled = (float*)w; w += (size_t)Gg * Hh * sizeof(float);
    float* cntg   = (float*)w; w += (size_t)Gg * sizeof(float);
    int*   qlist  = (int*)w;   w += (size_t)Qq * sizeof(int);
    int*   perm_e = (int*)w;   w += (size_t)Ee * sizeof(int);
    int*   hist   = (int*)w;   w += (size_t)Nn * sizeof(int);
    int*   cursor = (int*)w;   w += (size_t)Nn * sizeof(int);
    int*   qcnt   = (int*)w;   w += 16;
    unsigned short* wbuf = (unsigned short*)w;   // 3 layers x 135168 bf16

    const size_t LSTRIDE = 135168;
    const size_t oWq1 = 0, oWq2 = 20480, oWe1 = 36864, oWe2 = 69632, oWn1 = 86016, oWn2 = 118784;

    // --- counting sort: edges by dst ---
    hipMemsetAsync(hist, 0, Nn * sizeof(int), stream);
    k_hist<<<(Ee + 255) / 256, 256, 0, stream>>>(dst, Ee, Nn, hist);
    k_scan<<<1, 1024, 0, stream>>>(hist, cursor, (int*)nullptr);
    k_scatter<<<(Ee + 255) / 256, 256, 0, stream>>>(dst, Ee, Nn, cursor, perm_e);
    // --- counting sort: quadruplets by k_idx, fused with compaction (k<Nn) ---
    hipMemsetAsync(hist, 0, Nn * sizeof(int), stream);
    k_hist<<<(Qq + 255) / 256, 256, 0, stream>>>(k_idx, Qq, Nn, hist);
    k_scan<<<1, 1024, 0, stream>>>(hist, cursor, qcnt);
    k_scatter<<<(Qq + 255) / 256, 256, 0, stream>>>(k_idx, Qq, Nn, cursor, qlist);

    k_h0<<<(Nn * Hh + 255) / 256, 256, 0, stream>>>(x, hb0);

    for (int p = 0; p < 3; ++p) {
        unsigned short* base = wbuf + p * LSTRIDE;
        k_wt<<<(128 * 160 + 255) / 256, 256, 0, stream>>>(W_e1a + (size_t)p * 146 * 128, base + oWq1, 146, 160);
        k_wt<<<(128 * 128 + 255) / 256, 256, 0, stream>>>(W_e1b + (size_t)p * 128 * 128, base + oWq2, 128, 128);
        k_wt<<<(128 * 256 + 255) / 256, 256, 0, stream>>>(W_e2a + (size_t)p * 256 * 128, base + oWe1, 256, 256);
        k_wt<<<(128 * 128 + 255) / 256, 256, 0, stream>>>(W_e2b + (size_t)p * 128 * 128, base + oWe2, 128, 128);
        k_wt<<<(128 * 256 + 255) / 256, 256, 0, stream>>>(W_na  + (size_t)p * 256 * 128, base + oWn1, 256, 256);
        k_wt<<<(128 * 128 + 255) / 256, 256, 0, stream>>>(W_nb  + (size_t)p * 128 * 128, base + oWn2, 128, 128);
    }

    unsigned short* bufs[2] = { hb0, hb1 };
    int cur = 0;
    for (int p = 0; p < 3; ++p) {
        unsigned short* base = wbuf + p * LSTRIDE;
        hipMemsetAsync(agg2, 0, NHf, stream);
        hipMemsetAsync(aggr, 0, NHf, stream);
        k_quad<<<2048, 256, 0, stream>>>(bufs[cur], rbf, cbf, sbf, l_idx, k_idx,
            qlist, qcnt,
            base + oWq1, b_e1a + (size_t)p * 128,
            base + oWq2, b_e1b + (size_t)p * 128, agg2);
        k_cvt<<<(Nn * Hh / 4 + 255) / 256, 256, 0, stream>>>(agg2, agg2b, Nn * Hh);
        k_edge<<<1024, 256, 0, stream>>>(bufs[cur], agg2b, src, dst, perm_e,
            base + oWe1, b_e2a + (size_t)p * 128,
            base + oWe2, b_e2b + (size_t)p * 128, aggr);
        k_node<<<(Nn + 63) / 64, 256, 0, stream>>>(bufs[cur], aggr,
            base + oWn1, b_na + (size_t)p * 128,
            base + oWn2, b_nb + (size_t)p * 128, bufs[cur ^ 1]);
        cur ^= 1;
    }
    hipMemsetAsync(pooled, 0, (size_t)Gg * Hh * sizeof(float), stream);
    hipMemsetAsync(cntg, 0, (size_t)Gg * sizeof(float), stream);
    k_pool<<<(Nn + 195) / 196, 256, 0, stream>>>(bufs[cur], batch, pooled, cntg);
    k_final<<<Gg, 128, 0, stream>>>(pooled, cntg, W_oa, b_oa, W_ob, b_ob, (float*)d_out);
}